// Round 2
// baseline (27513.251 us; speedup 1.0000x reference)
//
#include <hip/hip_runtime.h>
#include <hip/hip_cooperative_groups.h>
#include <cstddef>

namespace cg = cooperative_groups;

// Problem constants
#define LL 512
#define BB 64
#define EE 512
#define HH 512
#define TT 16
#define START_TAG 14
#define STOP_TAG 15

__device__ __forceinline__ float rdlane(float v, int l) {
  return __builtin_bit_cast(float, __builtin_amdgcn_readlane(__builtin_bit_cast(int, v), l));
}

__device__ __forceinline__ unsigned short f2bf(float f) {
  unsigned u = __builtin_bit_cast(unsigned, f);
  unsigned r = u + 0x7FFFu + ((u >> 16) & 1u);
  return (unsigned short)(r >> 16);
}

template <typename XT> __device__ __forceinline__ float ldx(const XT* p);
template <> __device__ __forceinline__ float ldx<float>(const float* p) { return *p; }
template <> __device__ __forceinline__ float ldx<unsigned short>(const unsigned short* p) {
  return __builtin_bit_cast(float, (unsigned)(*p) << 16);
}

template <typename XT> __device__ __forceinline__ void store8(XT* p, const float* v);
template <> __device__ __forceinline__ void store8<float>(float* p, const float* v) {
  *(float4*)p = make_float4(v[0], v[1], v[2], v[3]);
  *(float4*)(p + 4) = make_float4(v[4], v[5], v[6], v[7]);
}
template <> __device__ __forceinline__ void store8<unsigned short>(unsigned short* p, const float* v) {
  ushort4 a, b;
  a.x = f2bf(v[0]); a.y = f2bf(v[1]); a.z = f2bf(v[2]); a.w = f2bf(v[3]);
  b.x = f2bf(v[4]); b.y = f2bf(v[5]); b.z = f2bf(v[6]); b.w = f2bf(v[7]);
  *(ushort4*)p = a;
  *(ushort4*)(p + 4) = b;
}

// ---------------------------------------------------------------------------
// K1: XP[m][n] = embed[tok(m)] . Wih_dir[n] + b_dir[n]
// m = l*64 + b (xt layout), n in [0,4096): n<2048 -> fwd, else bwd
// 128x128 tile, BK=16, 256 threads, 8x8 per thread. f32 VALU GEMM.
// ---------------------------------------------------------------------------
#define AP 132  // padded LDS leading dim (multiple of 4 keeps float4 alignment)

template <typename XT>
__global__ __launch_bounds__(256) void gemm_xp(
    const int* __restrict__ sent, const float* __restrict__ embed,
    const float* __restrict__ Wf, const float* __restrict__ Wb,
    const float* __restrict__ bf, const float* __restrict__ bb,
    XT* __restrict__ XPf, XT* __restrict__ XPb)
{
  __shared__ float Al[16 * AP];
  __shared__ float Bl[16 * AP];
  __shared__ int tok[128];

  const int bid = blockIdx.x;
  const int mt = bid & 255;       // 256 m-tiles
  const int nt = bid >> 8;        // 32 n-tiles
  const int m0 = mt << 7;
  const int n0g = nt << 7;
  const int dir = n0g >> 11;      // 0 fwd / 1 bwd
  const int n0 = n0g & 2047;
  const float* W = dir ? Wb : Wf;
  const float* bias = dir ? bb : bf;
  XT* XP = dir ? XPb : XPf;
  const int tid = threadIdx.x;

  if (tid < 128) {
    int m = m0 + tid;
    int l = m >> 6, b = m & 63;
    tok[tid] = sent[b * LL + l];
  }
  __syncthreads();

  float acc[8][8];
#pragma unroll
  for (int i = 0; i < 8; ++i)
#pragma unroll
    for (int j = 0; j < 8; ++j) acc[i][j] = 0.f;

  const int ty = tid >> 4, tx = tid & 15;

#pragma unroll 1
  for (int k0 = 0; k0 < EE; k0 += 16) {
    __syncthreads();
    // stage tiles (transposed into [k][row])
    for (int i = tid; i < 512; i += 256) {
      int row = i >> 2, q = i & 3;
      float4 va = *(const float4*)(embed + (size_t)tok[row] * EE + k0 + q * 4);
      Al[(q * 4 + 0) * AP + row] = va.x;
      Al[(q * 4 + 1) * AP + row] = va.y;
      Al[(q * 4 + 2) * AP + row] = va.z;
      Al[(q * 4 + 3) * AP + row] = va.w;
      float4 vb = *(const float4*)(W + (size_t)(n0 + row) * EE + k0 + q * 4);
      Bl[(q * 4 + 0) * AP + row] = vb.x;
      Bl[(q * 4 + 1) * AP + row] = vb.y;
      Bl[(q * 4 + 2) * AP + row] = vb.z;
      Bl[(q * 4 + 3) * AP + row] = vb.w;
    }
    __syncthreads();
#pragma unroll
    for (int kk = 0; kk < 16; ++kk) {
      float4 a0 = *(const float4*)(Al + kk * AP + ty * 8);
      float4 a1 = *(const float4*)(Al + kk * AP + ty * 8 + 4);
      float4 b0 = *(const float4*)(Bl + kk * AP + tx * 8);
      float4 b1 = *(const float4*)(Bl + kk * AP + tx * 8 + 4);
      float av[8] = {a0.x, a0.y, a0.z, a0.w, a1.x, a1.y, a1.z, a1.w};
      float bv[8] = {b0.x, b0.y, b0.z, b0.w, b1.x, b1.y, b1.z, b1.w};
#pragma unroll
      for (int i = 0; i < 8; ++i)
#pragma unroll
        for (int j = 0; j < 8; ++j) acc[i][j] = fmaf(av[i], bv[j], acc[i][j]);
    }
  }

  float4 bv0 = *(const float4*)(bias + n0 + tx * 8);
  float4 bv1 = *(const float4*)(bias + n0 + tx * 8 + 4);
#pragma unroll
  for (int i = 0; i < 8; ++i) {
    int m = m0 + ty * 8 + i;
    float row[8] = {acc[i][0] + bv0.x, acc[i][1] + bv0.y, acc[i][2] + bv0.z,
                    acc[i][3] + bv0.w, acc[i][4] + bv1.x, acc[i][5] + bv1.y,
                    acc[i][6] + bv1.z, acc[i][7] + bv1.w};
    store8<XT>(XP + (size_t)m * 2048 + n0 + tx * 8, row);
  }
}

// ---------------------------------------------------------------------------
// K2: cooperative BiLSTM recurrence. 256 blocks x 256 threads.
// block 0-127: fwd, 128-255: bwd. Block owns 4 hidden cols (16 gate cols).
// Whh slice persistent in VGPRs (K-split over 4 waves, 2 k / lane),
// broadcast via v_readlane. h double-buffered in global, [k][b] layout.
// ---------------------------------------------------------------------------
template <typename XT>
__global__ __launch_bounds__(256) void lstm_rec(
    const XT* __restrict__ XPf, const XT* __restrict__ XPb,
    const float* __restrict__ Whh_f, const float* __restrict__ Whh_b,
    const float* __restrict__ h0, const float* __restrict__ c0,
    float* __restrict__ hbuf,   // [2 dirs][2 bufs][512*64]
    float* __restrict__ hs)     // [32768][1024]
{
  extern __shared__ float part[];   // [4][64][20] = 20480 B
  cg::grid_group grid = cg::this_grid();

  const int wg = blockIdx.x;
  const int dir = wg >> 7;
  const int n0 = (wg & 127) << 2;
  const int tid = threadIdx.x;
  const int wv = tid >> 6;
  const int lane = tid & 63;
  const int kbase = wv << 7;

  const float* Whh = dir ? Whh_b : Whh_f;
  const XT* XP = dir ? XPb : XPf;
  float* hA = hbuf + dir * (2 * HH * BB);
  float* hB = hA + HH * BB;

  // persistent weights: wr{j}[c] = Whh[gcol(c)][kbase + 2*lane + j]
  float wr0[16], wr1[16];
#pragma unroll
  for (int c = 0; c < 16; ++c) {
    const int gcol = (c >> 2) * HH + n0 + (c & 3);
    wr0[c] = Whh[(size_t)gcol * HH + kbase + 2 * lane];
    wr1[c] = Whh[(size_t)gcol * HH + kbase + 2 * lane + 1];
  }

  const int cb = tid >> 2, cj = tid & 3;
  float creg = c0[dir * (BB * HH) + cb * HH + n0 + cj];
  hA[(n0 + cj) * BB + cb] = h0[dir * (BB * HH) + cb * HH + n0 + cj];
  grid.sync();

#pragma unroll 1
  for (int step = 0; step < LL; ++step) {
    const int t = dir ? (LL - 1 - step) : step;
    const float* hcur = (step & 1) ? hB : hA;
    float* hnxt = (step & 1) ? hA : hB;

    float acc[16];
#pragma unroll
    for (int c = 0; c < 16; ++c) acc[c] = 0.f;

    const float* hq = hcur + kbase * BB + lane;
    float h0a = hq[0], h1a = hq[64], h2a = hq[128], h3a = hq[192];
#pragma unroll 1
    for (int g = 0; g < 32; ++g) {
      float p0 = 0.f, p1 = 0.f, p2 = 0.f, p3 = 0.f;
      if (g < 31) {
        const float* nq = hq + (g + 1) * 256;
        p0 = nq[0]; p1 = nq[64]; p2 = nq[128]; p3 = nq[192];
      }
      const int k2 = g * 2;  // owner lanes k2, k2+1
#pragma unroll
      for (int c = 0; c < 16; ++c) {
        acc[c] = fmaf(h1a, rdlane(wr1[c], k2), fmaf(h0a, rdlane(wr0[c], k2), acc[c]));
        acc[c] = fmaf(h3a, rdlane(wr1[c], k2 + 1), fmaf(h2a, rdlane(wr0[c], k2 + 1), acc[c]));
      }
      h0a = p0; h1a = p1; h2a = p2; h3a = p3;
    }

    // write wave partials
    float* pp = part + (wv * 64 + lane) * 20;
#pragma unroll
    for (int c = 0; c < 16; c += 4)
      *(float4*)(pp + c) = make_float4(acc[c], acc[c + 1], acc[c + 2], acc[c + 3]);
    __syncthreads();

    // cell update: thread -> (b = cb, col j = cj)
    float gsum[4];
#pragma unroll
    for (int gi = 0; gi < 4; ++gi) {
      const int c = gi * 4 + cj;
      float s = part[(0 * 64 + cb) * 20 + c] + part[(1 * 64 + cb) * 20 + c] +
                part[(2 * 64 + cb) * 20 + c] + part[(3 * 64 + cb) * 20 + c];
      s += ldx<XT>(XP + ((size_t)t * BB + cb) * 2048 + gi * HH + n0 + cj);
      gsum[gi] = s;
    }
    const float ig = 1.f / (1.f + expf(-gsum[0]));
    const float fg = 1.f / (1.f + expf(-gsum[1]));
    const float gg = tanhf(gsum[2]);
    const float og = 1.f / (1.f + expf(-gsum[3]));
    creg = fg * creg + ig * gg;
    const float hv = og * tanhf(creg);
    hnxt[(n0 + cj) * BB + cb] = hv;
    hs[((size_t)t * BB + cb) * 1024 + dir * HH + n0 + cj] = hv;

    grid.sync();
  }
}

// ---------------------------------------------------------------------------
// K3a: feats[b][l][tag] = hs[l*64+b][:] . W_tag[tag][:] + b_tag[tag]
// ---------------------------------------------------------------------------
__global__ __launch_bounds__(64) void feats_k(
    const float* __restrict__ hs, const float* __restrict__ Wt,
    const float* __restrict__ bt, float* __restrict__ feats)
{
  const int bid = blockIdx.x;
  const int l = bid >> 6, b = bid & 63;
  const int tid = threadIdx.x;
  const int tag = tid & 15, q = tid >> 4;
  const float* hrow = hs + ((size_t)l * BB + b) * 1024;
  const float* wrow = Wt + tag * 1024;
  float p = 0.f;
#pragma unroll 4
  for (int i = 0; i < 64; ++i) {
    int k = q * 256 + i * 4;
    float4 h4 = *(const float4*)(hrow + k);
    float4 w4 = *(const float4*)(wrow + k);
    p += h4.x * w4.x + h4.y * w4.y + h4.z * w4.z + h4.w * w4.w;
  }
  p += __shfl_xor(p, 16);
  p += __shfl_xor(p, 32);
  if (q == 0) feats[((size_t)b * LL + l) * TT + tag] = p + bt[tag];
}

// ---------------------------------------------------------------------------
// K3b: Viterbi per sentence. Strict '>' preserves jnp.argmax tie-break.
// ---------------------------------------------------------------------------
__global__ __launch_bounds__(64) void viterbi_k(
    const float* __restrict__ feats, const float* __restrict__ trans,
    float* __restrict__ out)
{
  __shared__ float fv[TT];
  __shared__ unsigned char bps[LL * TT];
  const int b = blockIdx.x;
  const int tid = threadIdx.x;

  float trow[16];
  if (tid < 16) {
#pragma unroll
    for (int p = 0; p < 16; ++p) trow[p] = trans[tid * TT + p];
    fv[tid] = (tid == START_TAG) ? 0.f : -10000.f;
  }
  __syncthreads();

  const float* fb = feats + (size_t)b * LL * TT;
#pragma unroll 1
  for (int t = 0; t < LL; ++t) {
    float best = 0.f; int barg = 0;
    if (tid < 16) {
      best = fv[0] + trow[0]; barg = 0;
#pragma unroll
      for (int p = 1; p < 16; ++p) {
        float s = fv[p] + trow[p];
        if (s > best) { best = s; barg = p; }
      }
      bps[t * TT + tid] = (unsigned char)barg;
    }
    __syncthreads();
    if (tid < 16) fv[tid] = best + fb[t * TT + tid];
    __syncthreads();
  }

  if (tid == 0) {
    float bsc = fv[0] + trans[STOP_TAG * TT + 0];
    int btag = 0;
#pragma unroll
    for (int j = 1; j < 16; ++j) {
      float s = fv[j] + trans[STOP_TAG * TT + j];
      if (s > bsc) { bsc = s; btag = j; }
    }
    out[b] = bsc;
    int tg = btag;
    for (int t = LL - 1; t >= 0; --t) {
      out[BB + b * LL + t] = (float)tg;
      tg = bps[t * TT + tg];
    }
  }
}

// ---------------------------------------------------------------------------
extern "C" void kernel_launch(void* const* d_in, const int* in_sizes, int n_in,
                              void* d_out, int out_size, void* d_ws, size_t ws_size,
                              hipStream_t stream)
{
  (void)in_sizes; (void)n_in; (void)out_size;
  const int* sent = (const int*)d_in[0];
  const float* embed = (const float*)d_in[1];
  const float* Whh_f = (const float*)d_in[3];
  const float* b_f = (const float*)d_in[4];
  const float* Whh_b = (const float*)d_in[6];
  const float* b_b = (const float*)d_in[7];
  const float* h0 = (const float*)d_in[8];
  const float* c0 = (const float*)d_in[9];
  const float* Wt = (const float*)d_in[10];
  const float* bt = (const float*)d_in[11];
  const float* trans = (const float*)d_in[12];
  const float* Wih_f = (const float*)d_in[2];
  const float* Wih_b = (const float*)d_in[5];
  float* out = (float*)d_out;

  const size_t XPE = 67108864ULL;           // XP elements per dir
  const size_t HS_B = 134217728ULL;         // hs bytes (fp32)
  const size_t HBUF_B = 524288ULL;          // h double-buffer bytes
  const size_t FEATS_B = 2097152ULL;        // feats bytes
  const size_t needA = 2 * XPE * 4 + HS_B + HBUF_B + FEATS_B;  // ~643 MiB
  const size_t needB = 2 * XPE * 2 + HS_B + HBUF_B + FEATS_B;  // ~387 MiB

  char* wsb = (char*)d_ws;

  if (ws_size >= needA) {
    float* XPf = (float*)wsb;
    float* XPb = (float*)(wsb + XPE * 4);
    float* hs = (float*)(wsb + 2 * XPE * 4);
    float* hbuf = (float*)(wsb + 2 * XPE * 4 + HS_B);
    float* feats = (float*)(wsb + 2 * XPE * 4 + HS_B + HBUF_B);

    hipLaunchKernelGGL((gemm_xp<float>), dim3(8192), dim3(256), 0, stream,
                       sent, embed, Wih_f, Wih_b, b_f, b_b, XPf, XPb);
    void* ka[8] = {&XPf, &XPb, &Whh_f, &Whh_b, &h0, &c0, &hbuf, &hs};
    hipLaunchCooperativeKernel((void*)(lstm_rec<float>), dim3(256), dim3(256),
                               ka, 20480, stream);
    hipLaunchKernelGGL(feats_k, dim3(32768), dim3(64), 0, stream, hs, Wt, bt, feats);
    hipLaunchKernelGGL(viterbi_k, dim3(64), dim3(64), 0, stream, feats, trans, out);
  } else if (ws_size >= needB) {
    unsigned short* XPf = (unsigned short*)wsb;
    unsigned short* XPb = (unsigned short*)(wsb + XPE * 2);
    float* hs = (float*)(wsb + 2 * XPE * 2);
    float* hbuf = (float*)(wsb + 2 * XPE * 2 + HS_B);
    float* feats = (float*)(wsb + 2 * XPE * 2 + HS_B + HBUF_B);

    hipLaunchKernelGGL((gemm_xp<unsigned short>), dim3(8192), dim3(256), 0, stream,
                       sent, embed, Wih_f, Wih_b, b_f, b_b, XPf, XPb);
    void* ka[8] = {&XPf, &XPb, &Whh_f, &Whh_b, &h0, &c0, &hbuf, &hs};
    hipLaunchCooperativeKernel((void*)(lstm_rec<unsigned short>), dim3(256), dim3(256),
                               ka, 20480, stream);
    hipLaunchKernelGGL(feats_k, dim3(32768), dim3(64), 0, stream, hs, Wt, bt, feats);
    hipLaunchKernelGGL(viterbi_k, dim3(64), dim3(64), 0, stream, feats, trans, out);
  }
  // else: ws too small for this design — launch nothing (clean absmax-diagnostic
  // failure instead of a device fault); next revision switches to fused layout.
}

// Round 4
// 16184.818 us; speedup vs baseline: 1.6999x; 1.6999x over previous
//
#include <hip/hip_runtime.h>
#include <cstddef>

// Problem constants
#define LL 512
#define BB 64
#define EE 512
#define HH 512
#define TT 16
#define START_TAG 14
#define STOP_TAG 15
#define NBLK_DIR 64u   // lstm blocks per direction

__device__ __forceinline__ unsigned short f2bf(float f) {
  unsigned u = __builtin_bit_cast(unsigned, f);
  unsigned r = u + 0x7FFFu + ((u >> 16) & 1u);
  return (unsigned short)(r >> 16);
}

template <typename XT> __device__ __forceinline__ float ldx(const XT* p);
template <> __device__ __forceinline__ float ldx<float>(const float* p) { return *p; }
template <> __device__ __forceinline__ float ldx<unsigned short>(const unsigned short* p) {
  return __builtin_bit_cast(float, (unsigned)(*p) << 16);
}
template <typename XT> __device__ __forceinline__ void stx(XT* p, float v);
template <> __device__ __forceinline__ void stx<float>(float* p, float v) { *p = v; }
template <> __device__ __forceinline__ void stx<unsigned short>(unsigned short* p, float v) { *p = f2bf(v); }

// ---------------------------------------------------------------------------
// K1: XPT[t][col][g][b] = embed[tok(t,b)] . Wih_dir[g*512+col] + b_dir[...]
// 128x128 tile, BK=16, 256 threads, 8x8 per thread. f32 VALU GEMM.
// Output layout transposed for coalesced lstm reads.
// ---------------------------------------------------------------------------
#define AP 132  // padded LDS leading dim

template <typename XT>
__global__ __launch_bounds__(256) void gemm_xp(
    const int* __restrict__ sent, const float* __restrict__ embed,
    const float* __restrict__ Wf, const float* __restrict__ Wb,
    const float* __restrict__ bf, const float* __restrict__ bb,
    XT* __restrict__ XPf, XT* __restrict__ XPb)
{
  __shared__ float Al[16 * AP];
  __shared__ float Bl[16 * AP];
  __shared__ int tok[128];

  const int bid = blockIdx.x;
  const int mt = bid & 255;       // 256 m-tiles
  const int nt = bid >> 8;        // 32 n-tiles
  const int m0 = mt << 7;
  const int n0g = nt << 7;
  const int dir = n0g >> 11;      // 0 fwd / 1 bwd
  const int n0 = n0g & 2047;
  const float* W = dir ? Wb : Wf;
  const float* bias = dir ? bb : bf;
  XT* XP = dir ? XPb : XPf;
  const int tid = threadIdx.x;

  if (tid < 128) {
    int m = m0 + tid;
    int l = m >> 6, b = m & 63;
    tok[tid] = sent[b * LL + l];
  }
  __syncthreads();

  float acc[8][8];
#pragma unroll
  for (int i = 0; i < 8; ++i)
#pragma unroll
    for (int j = 0; j < 8; ++j) acc[i][j] = 0.f;

  const int ty = tid >> 4, tx = tid & 15;

#pragma unroll 1
  for (int k0 = 0; k0 < EE; k0 += 16) {
    __syncthreads();
    for (int i = tid; i < 512; i += 256) {
      int row = i >> 2, q = i & 3;
      float4 va = *(const float4*)(embed + (size_t)tok[row] * EE + k0 + q * 4);
      Al[(q * 4 + 0) * AP + row] = va.x;
      Al[(q * 4 + 1) * AP + row] = va.y;
      Al[(q * 4 + 2) * AP + row] = va.z;
      Al[(q * 4 + 3) * AP + row] = va.w;
      float4 vb = *(const float4*)(W + (size_t)(n0 + row) * EE + k0 + q * 4);
      Bl[(q * 4 + 0) * AP + row] = vb.x;
      Bl[(q * 4 + 1) * AP + row] = vb.y;
      Bl[(q * 4 + 2) * AP + row] = vb.z;
      Bl[(q * 4 + 3) * AP + row] = vb.w;
    }
    __syncthreads();
#pragma unroll
    for (int kk = 0; kk < 16; ++kk) {
      float4 a0 = *(const float4*)(Al + kk * AP + ty * 8);
      float4 a1 = *(const float4*)(Al + kk * AP + ty * 8 + 4);
      float4 b0 = *(const float4*)(Bl + kk * AP + tx * 8);
      float4 b1 = *(const float4*)(Bl + kk * AP + tx * 8 + 4);
      float av[8] = {a0.x, a0.y, a0.z, a0.w, a1.x, a1.y, a1.z, a1.w};
      float bv[8] = {b0.x, b0.y, b0.z, b0.w, b1.x, b1.y, b1.z, b1.w};
#pragma unroll
      for (int i = 0; i < 8; ++i)
#pragma unroll
        for (int j = 0; j < 8; ++j) acc[i][j] = fmaf(av[i], bv[j], acc[i][j]);
    }
  }

  float bval[8];
#pragma unroll
  for (int j = 0; j < 8; ++j) bval[j] = bias[n0 + tx * 8 + j];

#pragma unroll
  for (int i = 0; i < 8; ++i) {
    const int m = m0 + ty * 8 + i;
    const int t = m >> 6, b = m & 63;
#pragma unroll
    for (int j = 0; j < 8; ++j) {
      const int n = n0 + tx * 8 + j;      // 0..2047 within direction
      const int col = n & 511, g = n >> 9;
      stx<XT>(XP + (((size_t)t * HH + col) * 4 + g) * BB + b, acc[i][j] + bval[j]);
    }
  }
}

// ---------------------------------------------------------------------------
// Lightweight per-direction grid barrier (monotonic phase, thread-0 spin).
// ---------------------------------------------------------------------------
__device__ __forceinline__ void dir_barrier(unsigned* cnt, unsigned* rel,
                                            unsigned phase) {
  __syncthreads();   // all waves of block drained (vmcnt before s_barrier)
  if (threadIdx.x == 0) {
    __threadfence();  // release: make this block's stores globally visible
    unsigned old = __hip_atomic_fetch_add(cnt, 1u, __ATOMIC_RELAXED,
                                          __HIP_MEMORY_SCOPE_AGENT);
    if (old == phase * NBLK_DIR - 1u) {
      __hip_atomic_store(rel, phase, __ATOMIC_RELEASE, __HIP_MEMORY_SCOPE_AGENT);
    } else {
      while (__hip_atomic_load(rel, __ATOMIC_ACQUIRE, __HIP_MEMORY_SCOPE_AGENT) < phase)
        __builtin_amdgcn_s_sleep(2);
    }
    __threadfence();  // acquire: invalidate stale cached h before next step
  }
  __syncthreads();
}

// ---------------------------------------------------------------------------
// K2: BiLSTM recurrence. 128 blocks x 512 threads (8 waves).
// dir = bid>>6. Block owns 8 hidden cols; wave wv owns col n0+wv, all 4 gates.
// lane = batch b. Weights via wave-uniform s_load (SGPR operand FMAs).
// No readlane, no LDS, no intra-step syncthreads. h in [k][b] layout.
// ---------------------------------------------------------------------------
template <typename XT>
__global__ __launch_bounds__(512) void lstm_rec(
    const XT* __restrict__ XPTf, const XT* __restrict__ XPTb,
    const float* __restrict__ Whh_f, const float* __restrict__ Whh_b,
    const float* __restrict__ h0, const float* __restrict__ c0,
    float* __restrict__ hbuf,       // [2 dir][2 buf][512 k][64 b]
    float* __restrict__ hs,         // [512*64][1024]
    unsigned* __restrict__ bar)     // cnt_f@0, cnt_b@32, rel_f@64, rel_b@96
{
  const int bid = blockIdx.x;
  const int dir = bid >> 6;
  const int blk = bid & 63;
  const int tid = threadIdx.x;
  const int wv = __builtin_amdgcn_readfirstlane(tid >> 6);
  const int lane = tid & 63;            // batch b
  const int col = (blk << 3) + wv;      // owned hidden column

  const float* Whh = dir ? Whh_b : Whh_f;
  const XT* XP = dir ? XPTb : XPTf;
  float* hA = hbuf + (size_t)dir * (2 * HH * BB);
  float* hB = hA + HH * BB;
  unsigned* cnt = bar + (dir ? 32 : 0);
  unsigned* rel = bar + (dir ? 96 : 64);

  const float* W0 = Whh + ((size_t)0 * HH + col) * HH;
  const float* W1 = Whh + ((size_t)1 * HH + col) * HH;
  const float* W2 = Whh + ((size_t)2 * HH + col) * HH;
  const float* W3 = Whh + ((size_t)3 * HH + col) * HH;

  float creg = c0[(size_t)dir * BB * HH + (size_t)lane * HH + col];
  hA[col * BB + lane] = h0[(size_t)dir * BB * HH + (size_t)lane * HH + col];

  unsigned phase = 1;
  dir_barrier(cnt, rel, phase++);

#pragma unroll 1
  for (int step = 0; step < LL; ++step) {
    const int t = dir ? (LL - 1 - step) : step;
    const float* hcur = (step & 1) ? hB : hA;
    float* hnxt = (step & 1) ? hA : hB;

    // XP prefetch (coalesced 256B/wave per gate), consumed after the k-loop
    const XT* xpp = XP + ((size_t)t * HH + col) * 4 * BB + lane;
    const float xp0 = ldx<XT>(xpp);
    const float xp1 = ldx<XT>(xpp + BB);
    const float xp2 = ldx<XT>(xpp + 2 * BB);
    const float xp3 = ldx<XT>(xpp + 3 * BB);

    float a0 = 0.f, a1 = 0.f, a2 = 0.f, a3 = 0.f;
#pragma unroll 4
    for (int k4 = 0; k4 < HH; k4 += 4) {
      const float4 w0 = *(const float4*)(W0 + k4);
      const float4 w1 = *(const float4*)(W1 + k4);
      const float4 w2 = *(const float4*)(W2 + k4);
      const float4 w3 = *(const float4*)(W3 + k4);
      const float hk0 = hcur[(k4 + 0) * BB + lane];
      const float hk1 = hcur[(k4 + 1) * BB + lane];
      const float hk2 = hcur[(k4 + 2) * BB + lane];
      const float hk3 = hcur[(k4 + 3) * BB + lane];
      a0 = fmaf(hk0, w0.x, a0); a1 = fmaf(hk0, w1.x, a1);
      a2 = fmaf(hk0, w2.x, a2); a3 = fmaf(hk0, w3.x, a3);
      a0 = fmaf(hk1, w0.y, a0); a1 = fmaf(hk1, w1.y, a1);
      a2 = fmaf(hk1, w2.y, a2); a3 = fmaf(hk1, w3.y, a3);
      a0 = fmaf(hk2, w0.z, a0); a1 = fmaf(hk2, w1.z, a1);
      a2 = fmaf(hk2, w2.z, a2); a3 = fmaf(hk2, w3.z, a3);
      a0 = fmaf(hk3, w0.w, a0); a1 = fmaf(hk3, w1.w, a1);
      a2 = fmaf(hk3, w2.w, a2); a3 = fmaf(hk3, w3.w, a3);
    }

    const float ig = 1.f / (1.f + expf(-(xp0 + a0)));
    const float fg = 1.f / (1.f + expf(-(xp1 + a1)));
    const float gg = tanhf(xp2 + a2);
    const float og = 1.f / (1.f + expf(-(xp3 + a3)));
    creg = fg * creg + ig * gg;
    const float hv = og * tanhf(creg);

    hnxt[col * BB + lane] = hv;                                   // coalesced
    hs[((size_t)t * BB + lane) * 1024 + dir * HH + col] = hv;     // scattered, posted

    dir_barrier(cnt, rel, phase++);
  }
}

// ---------------------------------------------------------------------------
// K3a: feats[b][l][tag] = hs[l*64+b][:] . W_tag[tag][:] + b_tag[tag]
// ---------------------------------------------------------------------------
__global__ __launch_bounds__(64) void feats_k(
    const float* __restrict__ hs, const float* __restrict__ Wt,
    const float* __restrict__ bt, float* __restrict__ feats)
{
  const int bid = blockIdx.x;
  const int l = bid >> 6, b = bid & 63;
  const int tid = threadIdx.x;
  const int tag = tid & 15, q = tid >> 4;
  const float* hrow = hs + ((size_t)l * BB + b) * 1024;
  const float* wrow = Wt + tag * 1024;
  float p = 0.f;
#pragma unroll 4
  for (int i = 0; i < 64; ++i) {
    int k = q * 256 + i * 4;
    float4 h4 = *(const float4*)(hrow + k);
    float4 w4 = *(const float4*)(wrow + k);
    p += h4.x * w4.x + h4.y * w4.y + h4.z * w4.z + h4.w * w4.w;
  }
  p += __shfl_xor(p, 16);
  p += __shfl_xor(p, 32);
  if (q == 0) feats[((size_t)b * LL + l) * TT + tag] = p + bt[tag];
}

// ---------------------------------------------------------------------------
// K3b: Viterbi per sentence. Strict '>' preserves jnp.argmax tie-break.
// ---------------------------------------------------------------------------
__global__ __launch_bounds__(64) void viterbi_k(
    const float* __restrict__ feats, const float* __restrict__ trans,
    float* __restrict__ out)
{
  __shared__ float fv[TT];
  __shared__ unsigned char bps[LL * TT];
  const int b = blockIdx.x;
  const int tid = threadIdx.x;

  float trow[16];
  if (tid < 16) {
#pragma unroll
    for (int p = 0; p < 16; ++p) trow[p] = trans[tid * TT + p];
    fv[tid] = (tid == START_TAG) ? 0.f : -10000.f;
  }
  __syncthreads();

  const float* fb = feats + (size_t)b * LL * TT;
#pragma unroll 1
  for (int t = 0; t < LL; ++t) {
    float best = 0.f; int barg = 0;
    if (tid < 16) {
      best = fv[0] + trow[0]; barg = 0;
#pragma unroll
      for (int p = 1; p < 16; ++p) {
        float s = fv[p] + trow[p];
        if (s > best) { best = s; barg = p; }
      }
      bps[t * TT + tid] = (unsigned char)barg;
    }
    __syncthreads();
    if (tid < 16) fv[tid] = best + fb[t * TT + tid];
    __syncthreads();
  }

  if (tid == 0) {
    float bsc = fv[0] + trans[STOP_TAG * TT + 0];
    int btag = 0;
#pragma unroll
    for (int j = 1; j < 16; ++j) {
      float s = fv[j] + trans[STOP_TAG * TT + j];
      if (s > bsc) { bsc = s; btag = j; }
    }
    out[b] = bsc;
    int tg = btag;
    for (int t = LL - 1; t >= 0; --t) {
      out[BB + b * LL + t] = (float)tg;
      tg = bps[t * TT + tg];
    }
  }
}

// ---------------------------------------------------------------------------
template <typename XT>
static void run_pipeline(const int* sent, const float* embed,
                         const float* Wih_f, const float* Whh_f, const float* b_f,
                         const float* Wih_b, const float* Whh_b, const float* b_b,
                         const float* h0, const float* c0,
                         const float* Wt, const float* bt, const float* trans,
                         float* out, char* wsb, hipStream_t stream)
{
  const size_t XPE = (size_t)LL * HH * 4 * BB;         // elements per dir
  XT* XPTf = (XT*)(wsb + 1024);
  XT* XPTb = XPTf + XPE;
  char* after_xp = (char*)(XPTb + XPE);
  float* hbuf = (float*)after_xp;                       // 512 KiB
  float* hs = (float*)(after_xp + 2 * 2 * HH * BB * 4); // 128 MiB
  float* feats = (float*)((char*)hs + (size_t)LL * BB * 1024 * 4);
  unsigned* bar = (unsigned*)wsb;

  hipMemsetAsync(wsb, 0, 1024, stream);   // barrier counters

  hipLaunchKernelGGL((gemm_xp<XT>), dim3(8192), dim3(256), 0, stream,
                     sent, embed, Wih_f, Wih_b, b_f, b_b, XPTf, XPTb);

  void* ka[9];
  ka[0] = (void*)&XPTf; ka[1] = (void*)&XPTb;
  ka[2] = (void*)&Whh_f; ka[3] = (void*)&Whh_b;
  ka[4] = (void*)&h0;  ka[5] = (void*)&c0;
  ka[6] = (void*)&hbuf; ka[7] = (void*)&hs; ka[8] = (void*)&bar;
  hipLaunchCooperativeKernel((void*)(lstm_rec<XT>), dim3(128), dim3(512),
                             ka, 0, stream);

  hipLaunchKernelGGL(feats_k, dim3(32768), dim3(64), 0, stream, hs, Wt, bt, feats);
  hipLaunchKernelGGL(viterbi_k, dim3(64), dim3(64), 0, stream, feats, trans, out);
}

extern "C" void kernel_launch(void* const* d_in, const int* in_sizes, int n_in,
                              void* d_out, int out_size, void* d_ws, size_t ws_size,
                              hipStream_t stream)
{
  (void)in_sizes; (void)n_in; (void)out_size;
  const int* sent = (const int*)d_in[0];
  const float* embed = (const float*)d_in[1];
  const float* Wih_f = (const float*)d_in[2];
  const float* Whh_f = (const float*)d_in[3];
  const float* b_f = (const float*)d_in[4];
  const float* Wih_b = (const float*)d_in[5];
  const float* Whh_b = (const float*)d_in[6];
  const float* b_b = (const float*)d_in[7];
  const float* h0 = (const float*)d_in[8];
  const float* c0 = (const float*)d_in[9];
  const float* Wt = (const float*)d_in[10];
  const float* bt = (const float*)d_in[11];
  const float* trans = (const float*)d_in[12];
  float* out = (float*)d_out;

  const size_t XPE = (size_t)LL * HH * 4 * BB;          // 67,108,864 per dir
  const size_t FIXED = 1024 + 2ull * 2 * HH * BB * 4    // bar + hbuf
                     + (size_t)LL * BB * 1024 * 4       // hs
                     + (size_t)BB * LL * TT * 4;        // feats
  const size_t needA = FIXED + 2 * XPE * 4;             // fp32 XP, ~643 MiB
  const size_t needB = FIXED + 2 * XPE * 2;             // bf16 XP, ~387 MiB

  char* wsb = (char*)d_ws;
  if (ws_size >= needA) {
    run_pipeline<float>(sent, embed, Wih_f, Whh_f, b_f, Wih_b, Whh_b, b_b,
                        h0, c0, Wt, bt, trans, out, wsb, stream);
  } else if (ws_size >= needB) {
    run_pipeline<unsigned short>(sent, embed, Wih_f, Whh_f, b_f, Wih_b, Whh_b, b_b,
                                 h0, c0, Wt, bt, trans, out, wsb, stream);
  }
  // else: ws too small — clean diagnostic failure rather than device fault.
}